// Round 1
// baseline (181.687 us; speedup 1.0000x reference)
//
#include <hip/hip_runtime.h>

#define VV 256
#define FF 64
#define CC 64
#define NN 64

// ---------------------------------------------------------------------------
// Kernel A: GraphLearn. Per block: one graph n, one 64-column tile.
// lane = column j, wave (rg) = 32-row slice of i. x[n,j,:] lives in VGPRs,
// x[n,i,:] is wave-uniform -> scalar loads. tmp values parked in LDS,
// normalized + written coalesced after the column sums are known.
// Also accumulates ajloss = sum(s^2) + 0.1*sum(s * ||xi-xj||^2) atomically.
// ---------------------------------------------------------------------------
__global__ __launch_bounds__(512) void gl_kernel(
    const float* __restrict__ x, const float* __restrict__ a,
    float* __restrict__ s_out, float* __restrict__ loss_out) {
  const int n = blockIdx.y;
  const int jt = blockIdx.x;
  const int tid = threadIdx.x;
  const int lane = tid & 63;
  const int rg = __builtin_amdgcn_readfirstlane(tid >> 6);  // 0..7, wave-uniform
  const int j = jt * 64 + lane;
  const float* xn = x + (size_t)n * VV * FF;

  __shared__ float tmp_lds[32 * 512];  // [ii][tid]
  __shared__ float l_st[8][64];
  __shared__ float l_st2[8][64];
  __shared__ float l_std2[8][64];
  __shared__ float l_inv[64];

  // column features -> registers (one-time, 16 x float4)
  float xj[FF];
#pragma unroll
  for (int f4 = 0; f4 < FF / 4; ++f4) {
    const float4 v = *reinterpret_cast<const float4*>(xn + (size_t)j * FF + f4 * 4);
    xj[4 * f4 + 0] = v.x; xj[4 * f4 + 1] = v.y;
    xj[4 * f4 + 2] = v.z; xj[4 * f4 + 3] = v.w;
  }
  // attention vector -> registers
  float ar[FF];
#pragma unroll
  for (int f4 = 0; f4 < FF / 4; ++f4) {
    const float4 v = *reinterpret_cast<const float4*>(a + f4 * 4);
    ar[4 * f4 + 0] = v.x; ar[4 * f4 + 1] = v.y;
    ar[4 * f4 + 2] = v.z; ar[4 * f4 + 3] = v.w;
  }

  float st = 0.f, st2 = 0.f, std2 = 0.f;
  for (int ii = 0; ii < 32; ++ii) {
    const int i = rg * 32 + ii;  // wave-uniform row
    const float4* xi = reinterpret_cast<const float4*>(xn + (size_t)i * FF);
    float sc0 = 0.f, sc1 = 0.f, sc2 = 0.f, sc3 = 0.f;
    float q0 = 0.f, q1 = 0.f, q2 = 0.f, q3 = 0.f;
#pragma unroll
    for (int f4 = 0; f4 < 16; ++f4) {
      const float4 xv = xi[f4];
      const float d0 = xv.x - xj[4 * f4 + 0];
      const float d1 = xv.y - xj[4 * f4 + 1];
      const float d2 = xv.z - xj[4 * f4 + 2];
      const float d3 = xv.w - xj[4 * f4 + 3];
      sc0 = fmaf(fabsf(d0), ar[4 * f4 + 0], sc0);
      sc1 = fmaf(fabsf(d1), ar[4 * f4 + 1], sc1);
      sc2 = fmaf(fabsf(d2), ar[4 * f4 + 2], sc2);
      sc3 = fmaf(fabsf(d3), ar[4 * f4 + 3], sc3);
      q0 = fmaf(d0, d0, q0); q1 = fmaf(d1, d1, q1);
      q2 = fmaf(d2, d2, q2); q3 = fmaf(d3, d3, q3);
    }
    const float score = (sc0 + sc1) + (sc2 + sc3);
    const float d2sum = (q0 + q1) + (q2 + q3);
    const float t = __expf(-fmaxf(score, 0.f));
    tmp_lds[ii * 512 + tid] = t;
    st += t;
    st2 = fmaf(t, t, st2);
    std2 = fmaf(t, d2sum, std2);
  }
  l_st[rg][lane] = st;
  l_st2[rg][lane] = st2;
  l_std2[rg][lane] = std2;
  __syncthreads();

  if (tid < 64) {  // wave 0: finalize per-column sums + losses
    float cs = 0.f, c2 = 0.f, cd = 0.f;
#pragma unroll
    for (int w = 0; w < 8; ++w) {
      cs += l_st[w][lane];
      c2 += l_st2[w][lane];
      cd += l_std2[w][lane];
    }
    const float inv = 1.0f / cs;
    l_inv[lane] = inv;
    float loss = c2 * inv * inv + 0.1f * cd * inv;
#pragma unroll
    for (int off = 32; off > 0; off >>= 1) loss += __shfl_down(loss, off, 64);
    if (lane == 0) atomicAdd(loss_out, loss);
  }
  __syncthreads();

  const float inv = l_inv[lane];
  float* sn = s_out + (size_t)n * VV * VV;
  for (int ii = 0; ii < 32; ++ii) {
    const int i = rg * 32 + ii;
    sn[(size_t)i * VV + j] = tmp_lds[ii * 512 + tid] * inv;  // coalesced
  }
}

// ---------------------------------------------------------------------------
// Kernel B: ChebyshevConv using d==1 => T0=I, T1=-s, T2=2*s*s - I.
// out = x@(th0-th2) - (s@x)@th1 + 2*((s*s)@x)@th2 ; gcn = relu(out).
// Block: one graph n, 64-row i-tile. lane = local row il, wave fg = 16-feature
// slice. s tiles staged in LDS; x rows + theta via wave-uniform scalar loads.
// ---------------------------------------------------------------------------
__global__ __launch_bounds__(256) void gcn_kernel(
    const float* __restrict__ x, const float* __restrict__ theta,
    const float* __restrict__ s, float* __restrict__ gcn) {
  const int n = blockIdx.y;
  const int it = blockIdx.x;
  const int tid = threadIdx.x;
  const int il = tid & 63;
  const int fg = __builtin_amdgcn_readfirstlane(tid >> 6);  // 0..3
  const int i = it * 64 + il;
  const int fb = fg * 16;
  const float* xn = x + (size_t)n * VV * FF;
  const float* sn = s + (size_t)n * VV * VV;

  __shared__ float sch[64][65];
  __shared__ float yl[256][33];
  __shared__ float red[4][64][65];

  float y1[16], y2[16];
#pragma unroll
  for (int k = 0; k < 16; ++k) { y1[k] = 0.f; y2[k] = 0.f; }

  for (int ch = 0; ch < 4; ++ch) {
    // stage 64x64 tile of s (coalesced)
#pragma unroll
    for (int k = 0; k < 16; ++k) {
      const int e = tid + k * 256;
      const int r = e >> 6, c = e & 63;
      sch[r][c] = sn[(size_t)(it * 64 + r) * VV + ch * 64 + c];
    }
    __syncthreads();
    for (int jj = 0; jj < 64; ++jj) {
      const float sv = sch[il][jj];
      const float sv2 = sv * sv;
      const float* xr = xn + (size_t)(ch * 64 + jj) * FF + fb;  // uniform
#pragma unroll
      for (int k = 0; k < 16; ++k) {
        const float xf = xr[k];
        y1[k] = fmaf(sv, xf, y1[k]);
        y2[k] = fmaf(sv2, xf, y2[k]);
      }
    }
    __syncthreads();
  }

  // park y1/y2 in LDS so the rolled ff-loop below can index them dynamically
#pragma unroll
  for (int k = 0; k < 16; ++k) {
    yl[tid][k] = y1[k];
    yl[tid][16 + k] = y2[k];
  }

  float po[64];
#pragma unroll
  for (int c = 0; c < CC; ++c) po[c] = 0.f;
  for (int ff = 0; ff < 16; ++ff) {
    const int f = fb + ff;
    const float Y1 = yl[tid][ff];
    const float Y2s = 2.0f * yl[tid][16 + ff];
    const float xv = xn[(size_t)i * FF + f];
    const float* t0 = theta + (size_t)f * CC;
    const float* t1 = theta + (size_t)(FF + f) * CC;
    const float* t2 = theta + (size_t)(2 * FF + f) * CC;
#pragma unroll
    for (int c = 0; c < CC; ++c) {
      po[c] = po[c] + xv * (t0[c] - t2[c]) - Y1 * t1[c] + Y2s * t2[c];
    }
  }
#pragma unroll
  for (int c = 0; c < CC; ++c) red[fg][il][c] = po[c];
  __syncthreads();

  float* gn = gcn + (size_t)n * VV * CC;
#pragma unroll
  for (int k = 0; k < 16; ++k) {
    const int e = tid + k * 256;
    const int r = e >> 6, c = e & 63;
    const float v = red[0][r][c] + red[1][r][c] + red[2][r][c] + red[3][r][c];
    gn[(size_t)(it * 64 + r) * CC + c] = fmaxf(v, 0.f);
  }
}

extern "C" void kernel_launch(void* const* d_in, const int* in_sizes, int n_in,
                              void* d_out, int out_size, void* d_ws, size_t ws_size,
                              hipStream_t stream) {
  const float* x = (const float*)d_in[0];      // (64,256,64)
  const float* a = (const float*)d_in[1];      // (64,)
  const float* theta = (const float*)d_in[2];  // (3,64,64)

  float* gcn = (float*)d_out;                                    // 1048576
  float* s = (float*)d_out + (size_t)NN * VV * CC;               // 4194304
  float* loss = (float*)d_out + (size_t)NN * VV * CC + (size_t)NN * VV * VV;

  hipMemsetAsync(loss, 0, sizeof(float), stream);
  gl_kernel<<<dim3(4, NN), 512, 0, stream>>>(x, a, s, loss);
  gcn_kernel<<<dim3(4, NN), 256, 0, stream>>>(x, theta, s, gcn);
}

// Round 2
// 142.211 us; speedup vs baseline: 1.2776x; 1.2776x over previous
//
#include <hip/hip_runtime.h>

#define VV 256
#define FF 64
#define CC 64
#define NN 64

// force a wave-uniform float into an SGPR
__device__ __forceinline__ float sload(const float* p) {
  return __uint_as_float(__builtin_amdgcn_readfirstlane(__float_as_uint(*p)));
}

// ---------------------------------------------------------------------------
// Kernel A: GraphLearn. Block = (n, 64-column tile), 1024 threads = 16 waves.
// lane = column j (x[n,j,:] in 64 VGPRs), wave rg owns 16 rows i (uniform ->
// scalar/broadcast loads). tmp values kept in 16 VGPRs (no big LDS).
// Writes column-normalized s and atomically accumulates ajloss.
// ---------------------------------------------------------------------------
__global__ __launch_bounds__(1024) void gl_kernel(
    const float* __restrict__ x, const float* __restrict__ a,
    float* __restrict__ s_out, float* __restrict__ loss_out) {
  const int n = blockIdx.y;
  const int jt = blockIdx.x;
  const int tid = threadIdx.x;
  const int lane = tid & 63;
  const int rg = __builtin_amdgcn_readfirstlane(tid >> 6);  // 0..15 uniform
  const int j = jt * 64 + lane;
  const float* xn = x + (size_t)n * VV * FF;

  __shared__ float l_st[16][64];
  __shared__ float l_st2[16][64];
  __shared__ float l_std2[16][64];
  __shared__ float l_inv[64];

  // column features -> VGPRs
  float xj[FF];
#pragma unroll
  for (int f4 = 0; f4 < FF / 4; ++f4) {
    const float4 v = *reinterpret_cast<const float4*>(xn + (size_t)j * FF + f4 * 4);
    xj[4 * f4 + 0] = v.x; xj[4 * f4 + 1] = v.y;
    xj[4 * f4 + 2] = v.z; xj[4 * f4 + 3] = v.w;
  }
  // attention vector -> SGPRs (uniform)
  float ar[FF];
#pragma unroll
  for (int k = 0; k < FF; ++k) ar[k] = sload(a + k);

  float tmp[16];
  float st = 0.f, st2 = 0.f, std2 = 0.f;
#pragma unroll
  for (int ii = 0; ii < 16; ++ii) {
    const int i = rg * 16 + ii;  // wave-uniform row
    const float4* xi = reinterpret_cast<const float4*>(xn + (size_t)i * FF);
    float sc0 = 0.f, sc1 = 0.f, sc2 = 0.f, sc3 = 0.f;
    float q0 = 0.f, q1 = 0.f, q2 = 0.f, q3 = 0.f;
#pragma unroll
    for (int f4 = 0; f4 < 16; ++f4) {
      const float4 xv = xi[f4];
      const float d0 = xv.x - xj[4 * f4 + 0];
      const float d1 = xv.y - xj[4 * f4 + 1];
      const float d2 = xv.z - xj[4 * f4 + 2];
      const float d3 = xv.w - xj[4 * f4 + 3];
      sc0 = fmaf(fabsf(d0), ar[4 * f4 + 0], sc0);
      sc1 = fmaf(fabsf(d1), ar[4 * f4 + 1], sc1);
      sc2 = fmaf(fabsf(d2), ar[4 * f4 + 2], sc2);
      sc3 = fmaf(fabsf(d3), ar[4 * f4 + 3], sc3);
      q0 = fmaf(d0, d0, q0); q1 = fmaf(d1, d1, q1);
      q2 = fmaf(d2, d2, q2); q3 = fmaf(d3, d3, q3);
    }
    const float score = (sc0 + sc1) + (sc2 + sc3);
    const float d2sum = (q0 + q1) + (q2 + q3);
    const float t = __expf(-fmaxf(score, 0.f));
    tmp[ii] = t;
    st += t;
    st2 = fmaf(t, t, st2);
    std2 = fmaf(t, d2sum, std2);
  }
  l_st[rg][lane] = st;
  l_st2[rg][lane] = st2;
  l_std2[rg][lane] = std2;
  __syncthreads();

  if (tid < 64) {  // wave 0: per-column sums + loss
    float cs = 0.f, c2 = 0.f, cd = 0.f;
#pragma unroll
    for (int w = 0; w < 16; ++w) {
      cs += l_st[w][lane];
      c2 += l_st2[w][lane];
      cd += l_std2[w][lane];
    }
    const float inv = 1.0f / cs;
    l_inv[lane] = inv;
    float loss = c2 * inv * inv + 0.1f * cd * inv;
#pragma unroll
    for (int off = 32; off > 0; off >>= 1) loss += __shfl_down(loss, off, 64);
    if (lane == 0) atomicAdd(loss_out, loss);
  }
  __syncthreads();

  const float inv = l_inv[lane];
  float* sn = s_out + (size_t)n * VV * VV;
#pragma unroll
  for (int ii = 0; ii < 16; ++ii) {
    sn[(size_t)(rg * 16 + ii) * VV + j] = tmp[ii] * inv;  // coalesced
  }
}

// ---------------------------------------------------------------------------
// Kernel B: ChebyshevConv with d==1 => T0=I, T1=-s, T2=2*s*s-I (elementwise):
//   out = x@(th0-th2) - (s@x)@th1 + 2*((s*s)@x)@th2 ; gcn = relu(out).
// Block = (n, 64-row tile), 1024 threads = 16 waves. lane = local row il,
// wave w owns a 4-feature slice for y-accum and 4 output columns for the
// epilogue. s tiles + x tile + y1/y2 staged in LDS (66 KB, odd strides).
// ---------------------------------------------------------------------------
__global__ __launch_bounds__(1024) void gcn_kernel(
    const float* __restrict__ x, const float* __restrict__ theta,
    const float* __restrict__ s, float* __restrict__ gcn) {
  const int n = blockIdx.y;
  const int it = blockIdx.x;
  const int tid = threadIdx.x;
  const int il = tid & 63;
  const int w = __builtin_amdgcn_readfirstlane(tid >> 6);  // 0..15 uniform
  const int fb = w * 4;
  const float* xn = x + (size_t)n * VV * FF;
  const float* sn = s + (size_t)n * VV * VV;

  __shared__ float sch[64][65];   // s tile (also reused as output transpose)
  __shared__ float xt[64][65];    // x rows of this i-tile
  __shared__ float yb[64][129];   // [il][f]=y1, [il][64+f]=y2

  // one-time stage of x tile (coalesced)
  {
    const int r = tid >> 4, c = (tid & 15) * 4;
    const float4 v = *reinterpret_cast<const float4*>(
        xn + (size_t)(it * 64 + r) * FF + c);
    xt[r][c + 0] = v.x; xt[r][c + 1] = v.y;
    xt[r][c + 2] = v.z; xt[r][c + 3] = v.w;
  }

  float y1[4] = {0.f, 0.f, 0.f, 0.f};
  float y2[4] = {0.f, 0.f, 0.f, 0.f};

  for (int ch = 0; ch < 4; ++ch) {
    // stage 64x64 tile of s (coalesced)
    {
      const int r = tid >> 4, c = (tid & 15) * 4;
      const float4 v = *reinterpret_cast<const float4*>(
          sn + (size_t)(it * 64 + r) * VV + ch * 64 + c);
      sch[r][c + 0] = v.x; sch[r][c + 1] = v.y;
      sch[r][c + 2] = v.z; sch[r][c + 3] = v.w;
    }
    __syncthreads();
#pragma unroll 8
    for (int jj = 0; jj < 64; ++jj) {
      const float sv = sch[il][jj];
      const float sv2 = sv * sv;
      const float* xr = xn + (size_t)(ch * 64 + jj) * FF + fb;  // uniform
      const float x0 = xr[0], x1 = xr[1], x2 = xr[2], x3 = xr[3];
      y1[0] = fmaf(sv, x0, y1[0]); y2[0] = fmaf(sv2, x0, y2[0]);
      y1[1] = fmaf(sv, x1, y1[1]); y2[1] = fmaf(sv2, x1, y2[1]);
      y1[2] = fmaf(sv, x2, y1[2]); y2[2] = fmaf(sv2, x2, y2[2]);
      y1[3] = fmaf(sv, x3, y1[3]); y2[3] = fmaf(sv2, x3, y2[3]);
    }
    __syncthreads();
  }

  // park y1/y2 slices
#pragma unroll
  for (int k = 0; k < 4; ++k) {
    yb[il][fb + k] = y1[k];
    yb[il][64 + fb + k] = y2[k];
  }
  __syncthreads();

  // epilogue: wave w computes columns cb..cb+3 for its lane's row il
  const int cb = w * 4;
  float po[4] = {0.f, 0.f, 0.f, 0.f};
#pragma unroll 4
  for (int f = 0; f < FF; ++f) {
    const float xv = xt[il][f];
    const float Y1 = yb[il][f];
    const float Y2 = yb[il][64 + f];
    const float z = fmaf(2.0f, Y2, -xv);  // 2*y2 - x
    const float* t0 = theta + (size_t)f * CC + cb;               // uniform
    const float* t1 = theta + (size_t)(FF + f) * CC + cb;        // uniform
    const float* t2 = theta + (size_t)(2 * FF + f) * CC + cb;    // uniform
#pragma unroll
    for (int cc = 0; cc < 4; ++cc) {
      po[cc] = fmaf(xv, t0[cc], po[cc]);
      po[cc] = fmaf(z, t2[cc], po[cc]);
      po[cc] = fmaf(-Y1, t1[cc], po[cc]);
    }
  }

  // transpose through sch for coalesced store
#pragma unroll
  for (int cc = 0; cc < 4; ++cc) sch[il][cb + cc] = po[cc];
  __syncthreads();
  {
    const int r = tid >> 4, c = (tid & 15) * 4;
    float4 o;
    o.x = fmaxf(sch[r][c + 0], 0.f);
    o.y = fmaxf(sch[r][c + 1], 0.f);
    o.z = fmaxf(sch[r][c + 2], 0.f);
    o.w = fmaxf(sch[r][c + 3], 0.f);
    *reinterpret_cast<float4*>(
        gcn + (size_t)n * VV * CC + (size_t)(it * 64 + r) * CC + c) = o;
  }
}

extern "C" void kernel_launch(void* const* d_in, const int* in_sizes, int n_in,
                              void* d_out, int out_size, void* d_ws, size_t ws_size,
                              hipStream_t stream) {
  const float* x = (const float*)d_in[0];      // (64,256,64)
  const float* a = (const float*)d_in[1];      // (64,)
  const float* theta = (const float*)d_in[2];  // (3,64,64)

  float* gcn = (float*)d_out;                                    // 1048576
  float* s = (float*)d_out + (size_t)NN * VV * CC;               // 4194304
  float* loss = (float*)d_out + (size_t)NN * VV * CC + (size_t)NN * VV * VV;

  hipMemsetAsync(loss, 0, sizeof(float), stream);
  gl_kernel<<<dim3(4, NN), 1024, 0, stream>>>(x, a, s, loss);
  gcn_kernel<<<dim3(4, NN), 1024, 0, stream>>>(x, theta, s, gcn);
}

// Round 3
// 107.299 us; speedup vs baseline: 1.6933x; 1.3254x over previous
//
#include <hip/hip_runtime.h>
#include <hip/hip_fp16.h>
#include <hip/hip_bf16.h>

#define VV 256
#define FF 64
#define CC 64
#define NN 64

typedef short bf16x8 __attribute__((ext_vector_type(8)));
typedef float f32x4v __attribute__((ext_vector_type(4)));

__device__ __forceinline__ short f2bf(float f) {
  union { __hip_bfloat16 b; short s; } u;
  u.b = __float2bfloat16(f);
  return u.s;
}

// ---------------------------------------------------------------------------
// Kernel 0: convert x (fp32) -> half into ws; also a -> half2.
// ---------------------------------------------------------------------------
__global__ __launch_bounds__(256) void cvt_kernel(
    const float* __restrict__ x, const float* __restrict__ a,
    __half2* __restrict__ xh2, __half2* __restrict__ ah) {
  const int t = blockIdx.x * 256 + threadIdx.x;
  const float4* xv = reinterpret_cast<const float4*>(x);
  const float4 v0 = xv[2 * t], v1 = xv[2 * t + 1];
  __half2* out = xh2 + 4 * (size_t)t;
  out[0] = __floats2half2_rn(v0.x, v0.y);
  out[1] = __floats2half2_rn(v0.z, v0.w);
  out[2] = __floats2half2_rn(v1.x, v1.y);
  out[3] = __floats2half2_rn(v1.z, v1.w);
  if (blockIdx.x == 0 && threadIdx.x < 32)
    ah[threadIdx.x] = __floats2half2_rn(a[2 * threadIdx.x], a[2 * threadIdx.x + 1]);
}

// ---------------------------------------------------------------------------
// Kernel A: GraphLearn, packed-fp16 inner loop.
// Block = (jt, n): 64 columns (lane = j), 16 waves x 16 rows. 1024 thr.
// xj in 32 half2 VGPRs; xi rows wave-uniform (s_load of half2 from ws).
// Per 2 features: hsub2 + habs2 + hfma2(score) + hfma2(q) = 4 VALU.
// fp16 is safe: diag d==0 exactly; off-diag tmp ~ e^-100 ~ 0.
// ---------------------------------------------------------------------------
template <bool PRE>
__global__ __launch_bounds__(1024, 4) void gl_kernel(
    const float* __restrict__ x, const float* __restrict__ a,
    const __half* __restrict__ xh, const __half2* __restrict__ ah,
    float* __restrict__ s_out, float* __restrict__ loss_out) {
  const int n = blockIdx.y;
  const int jt = blockIdx.x;
  const int tid = threadIdx.x;
  const int lane = tid & 63;
  const int rg = __builtin_amdgcn_readfirstlane(tid >> 6);  // 0..15
  const int j = jt * 64 + lane;

  __shared__ float l_st[16][64];
  __shared__ float l_st2[16][64];
  __shared__ float l_std2[16][64];
  __shared__ float l_inv[64];

  // column features (packed half2) -> 32 VGPRs
  __half2 xj[32];
  if (PRE) {
    const __half2* xjp =
        reinterpret_cast<const __half2*>(xh + ((size_t)n * VV + j) * FF);
#pragma unroll
    for (int k = 0; k < 32; ++k) xj[k] = xjp[k];
  } else {
    const float* xjp = x + ((size_t)n * VV + j) * FF;
#pragma unroll
    for (int k = 0; k < 32; ++k) xj[k] = __floats2half2_rn(xjp[2 * k], xjp[2 * k + 1]);
  }
  // attention (packed) -> scalar regs
  __half2 a2r[32];
  if (PRE) {
    const unsigned* ap = reinterpret_cast<const unsigned*>(ah);
#pragma unroll
    for (int k = 0; k < 32; ++k) {
      union { unsigned u; __half2 h; } c;
      c.u = __builtin_amdgcn_readfirstlane(ap[k]);
      a2r[k] = c.h;
    }
  } else {
#pragma unroll
    for (int k = 0; k < 32; ++k) a2r[k] = __floats2half2_rn(a[2 * k], a[2 * k + 1]);
  }

  float tmp[16];
  float st = 0.f, st2 = 0.f, std2 = 0.f;
  const __half2 hz = __float2half2_rn(0.f);
#pragma unroll
  for (int ii = 0; ii < 16; ++ii) {
    const int row = rg * 16 + ii;  // wave-uniform
    __half2 sacc = hz, qacc = hz;
    if (PRE) {
      const __half2* xr =
          reinterpret_cast<const __half2*>(xh + ((size_t)n * VV + row) * FF);
#pragma unroll
      for (int f2 = 0; f2 < 32; ++f2) {
        const __half2 d = __hsub2(xr[f2], xj[f2]);
        sacc = __hfma2(__habs2(d), a2r[f2], sacc);
        qacc = __hfma2(d, d, qacc);
      }
    } else {
      const float* xr = x + ((size_t)n * VV + row) * FF;
#pragma unroll
      for (int f2 = 0; f2 < 32; ++f2) {
        const __half2 xi2 = __floats2half2_rn(xr[2 * f2], xr[2 * f2 + 1]);
        const __half2 d = __hsub2(xi2, xj[f2]);
        sacc = __hfma2(__habs2(d), a2r[f2], sacc);
        qacc = __hfma2(d, d, qacc);
      }
    }
    const float score = __low2float(sacc) + __high2float(sacc);
    const float q = __low2float(qacc) + __high2float(qacc);
    const float t = __expf(-fmaxf(score, 0.f));
    tmp[ii] = t;
    st += t;
    st2 = fmaf(t, t, st2);
    std2 = fmaf(t, q, std2);
  }
  l_st[rg][lane] = st;
  l_st2[rg][lane] = st2;
  l_std2[rg][lane] = std2;
  __syncthreads();

  if (tid < 64) {
    float cs = 0.f, c2 = 0.f, cd = 0.f;
#pragma unroll
    for (int w = 0; w < 16; ++w) {
      cs += l_st[w][lane];
      c2 += l_st2[w][lane];
      cd += l_std2[w][lane];
    }
    const float inv = 1.0f / cs;
    l_inv[lane] = inv;
    float loss = c2 * inv * inv + 0.1f * cd * inv;
#pragma unroll
    for (int off = 32; off > 0; off >>= 1) loss += __shfl_down(loss, off, 64);
    if (lane == 0) atomicAdd(loss_out, loss);
  }
  __syncthreads();

  const float inv = l_inv[lane];
  float* sn = s_out + (size_t)n * VV * VV;
#pragma unroll
  for (int ii = 0; ii < 16; ++ii)
    sn[(size_t)(rg * 16 + ii) * VV + j] = tmp[ii] * inv;  // coalesced
}

// ---------------------------------------------------------------------------
// Kernel B: ChebyshevConv via bf16 MFMA.
// d==1 => T0=I, T1=-s, T2=2*s*s-I (elementwise), so
//   out = relu( [x | s@x | (s.s)@x] @ [th0-th2 ; -th1 ; 2*th2] )  (K=192)
// Block = (it,n): 32 output rows, 256 thr = 4 waves. wave w: row-half wr=w&1,
// col-half wc=w>>1 (2 n-tiles of 16). Stage-1: K=256 in 4 chunks of 64,
// s & s^2 as A (bf16), x^T as B. Stage-2: yb=[x|y1|y2] (rows) @ thT.
// Fragment layouts (verified m89/m91/m120): A[m=lane&15][k=quad*8+j],
// B[k=quad*8+j][n=lane&15], C/D col=lane&15 row=quad*4+reg.
// ---------------------------------------------------------------------------
__global__ __launch_bounds__(256, 4) void gcn_kernel(
    const float* __restrict__ x, const float* __restrict__ theta,
    const float* __restrict__ s, float* __restrict__ gcn) {
  const int n = blockIdx.y;
  const int it = blockIdx.x;  // 0..7, 32 rows each
  const int tid = threadIdx.x;
  const int lane = tid & 63;
  const int w = __builtin_amdgcn_readfirstlane(tid >> 6);  // 0..3
  const int wr = w & 1;        // row half
  const int wc = w >> 1;       // col half
  const int l15 = lane & 15;
  const int quad = lane >> 4;

  __shared__ __attribute__((aligned(16))) char smem[38400];
  short* sb = (short*)smem;          // [32][72] bf16 s-tile
  short* s2b = sb + 32 * 72;         // [32][72] bf16 s^2-tile
  short* xbT = s2b + 32 * 72;        // [64][72] bf16 x^T-tile (feature-major)
  short* yb = (short*)smem;          // [32][200] bf16 [x|y1|y2]   (aliased)
  short* thT = yb + 32 * 200;        // [64][200] bf16 theta^T     (aliased)

  f32x4v acc1[2] = {{0.f, 0.f, 0.f, 0.f}, {0.f, 0.f, 0.f, 0.f}};
  f32x4v acc2[2] = {{0.f, 0.f, 0.f, 0.f}, {0.f, 0.f, 0.f, 0.f}};

  const float* sn = s + (size_t)n * VV * VV;
  const float* xn = x + (size_t)n * VV * FF;

  for (int kc = 0; kc < 4; ++kc) {
    // stage s / s^2 tile: 32 rows x 64 cols (coalesced fp32 reads)
    {
      const int r = tid >> 3, c = (tid & 7) * 8;
      const float* sp = sn + (size_t)(it * 32 + r) * VV + kc * 64 + c;
      const float4 v0 = *reinterpret_cast<const float4*>(sp);
      const float4 v1 = *reinterpret_cast<const float4*>(sp + 4);
      short4 b0, b1, q0, q1;
      b0.x = f2bf(v0.x); b0.y = f2bf(v0.y); b0.z = f2bf(v0.z); b0.w = f2bf(v0.w);
      b1.x = f2bf(v1.x); b1.y = f2bf(v1.y); b1.z = f2bf(v1.z); b1.w = f2bf(v1.w);
      q0.x = f2bf(v0.x * v0.x); q0.y = f2bf(v0.y * v0.y);
      q0.z = f2bf(v0.z * v0.z); q0.w = f2bf(v0.w * v0.w);
      q1.x = f2bf(v1.x * v1.x); q1.y = f2bf(v1.y * v1.y);
      q1.z = f2bf(v1.z * v1.z); q1.w = f2bf(v1.w * v1.w);
      *reinterpret_cast<short4*>(sb + r * 72 + c) = b0;
      *reinterpret_cast<short4*>(sb + r * 72 + c + 4) = b1;
      *reinterpret_cast<short4*>(s2b + r * 72 + c) = q0;
      *reinterpret_cast<short4*>(s2b + r * 72 + c + 4) = q1;
    }
    // stage x^T tile: 64 k-rows x 64 features, transposed into xbT[f][k]
    {
      const int r = tid >> 2, f0 = (tid & 3) * 16;
      const float* xp = xn + (size_t)(kc * 64 + r) * FF + f0;
#pragma unroll
      for (int g = 0; g < 4; ++g) {
        const float4 v = *reinterpret_cast<const float4*>(xp + 4 * g);
        xbT[(f0 + 4 * g + 0) * 72 + r] = f2bf(v.x);
        xbT[(f0 + 4 * g + 1) * 72 + r] = f2bf(v.y);
        xbT[(f0 + 4 * g + 2) * 72 + r] = f2bf(v.z);
        xbT[(f0 + 4 * g + 3) * 72 + r] = f2bf(v.w);
      }
    }
    __syncthreads();
#pragma unroll
    for (int kk = 0; kk < 2; ++kk) {
      const bf16x8 af = *reinterpret_cast<const bf16x8*>(
          sb + (wr * 16 + l15) * 72 + kk * 32 + quad * 8);
      const bf16x8 a2f = *reinterpret_cast<const bf16x8*>(
          s2b + (wr * 16 + l15) * 72 + kk * 32 + quad * 8);
#pragma unroll
      for (int t = 0; t < 2; ++t) {
        const int nt = 2 * wc + t;
        const bf16x8 bf = *reinterpret_cast<const bf16x8*>(
            xbT + (nt * 16 + l15) * 72 + kk * 32 + quad * 8);
        acc1[t] = __builtin_amdgcn_mfma_f32_16x16x32_bf16(af, bf, acc1[t], 0, 0, 0);
        acc2[t] = __builtin_amdgcn_mfma_f32_16x16x32_bf16(a2f, bf, acc2[t], 0, 0, 0);
      }
    }
    __syncthreads();  // also guards the aliasing write below on last iter
  }

  // ---- build stage-2 operands (aliased LDS) ----
  // yb x-part: rows 32, cols 0..63
  {
    const int r = tid >> 3, c = (tid & 7) * 8;
    const float* xp = xn + (size_t)(it * 32 + r) * FF + c;
    const float4 v0 = *reinterpret_cast<const float4*>(xp);
    const float4 v1 = *reinterpret_cast<const float4*>(xp + 4);
    short4 b0, b1;
    b0.x = f2bf(v0.x); b0.y = f2bf(v0.y); b0.z = f2bf(v0.z); b0.w = f2bf(v0.w);
    b1.x = f2bf(v1.x); b1.y = f2bf(v1.y); b1.z = f2bf(v1.z); b1.w = f2bf(v1.w);
    *reinterpret_cast<short4*>(yb + r * 200 + c) = b0;
    *reinterpret_cast<short4*>(yb + r * 200 + c + 4) = b1;
  }
  // yb y1/y2 parts from accumulators (C-layout scatter)
#pragma unroll
  for (int t = 0; t < 2; ++t) {
    const int col = (2 * wc + t) * 16 + l15;
#pragma unroll
    for (int r = 0; r < 4; ++r) {
      const int R = wr * 16 + quad * 4 + r;
      yb[R * 200 + 64 + col] = f2bf(acc1[t][r]);
      yb[R * 200 + 128 + col] = f2bf(acc2[t][r]);
    }
  }
  // thT: [out-col][k], k: 0..63 = th0-th2, 64..127 = -th1, 128..191 = 2*th2
  {
    const int r = tid >> 2, c0 = (tid & 3) * 16;
    const float* t0p = theta + (size_t)r * CC + c0;
    const float* t1p = theta + (size_t)(FF + r) * CC + c0;
    const float* t2p = theta + (size_t)(2 * FF + r) * CC + c0;
#pragma unroll
    for (int g = 0; g < 4; ++g) {
      const float4 v0 = *reinterpret_cast<const float4*>(t0p + 4 * g);
      const float4 v1 = *reinterpret_cast<const float4*>(t1p + 4 * g);
      const float4 v2 = *reinterpret_cast<const float4*>(t2p + 4 * g);
      const int cb = c0 + 4 * g;
      thT[(cb + 0) * 200 + r] = f2bf(v0.x - v2.x);
      thT[(cb + 1) * 200 + r] = f2bf(v0.y - v2.y);
      thT[(cb + 2) * 200 + r] = f2bf(v0.z - v2.z);
      thT[(cb + 3) * 200 + r] = f2bf(v0.w - v2.w);
      thT[(cb + 0) * 200 + 64 + r] = f2bf(-v1.x);
      thT[(cb + 1) * 200 + 64 + r] = f2bf(-v1.y);
      thT[(cb + 2) * 200 + 64 + r] = f2bf(-v1.z);
      thT[(cb + 3) * 200 + 64 + r] = f2bf(-v1.w);
      thT[(cb + 0) * 200 + 128 + r] = f2bf(2.f * v2.x);
      thT[(cb + 1) * 200 + 128 + r] = f2bf(2.f * v2.y);
      thT[(cb + 2) * 200 + 128 + r] = f2bf(2.f * v2.z);
      thT[(cb + 3) * 200 + 128 + r] = f2bf(2.f * v2.w);
    }
  }
  __syncthreads();

  // ---- stage-2 GEMM: out_tile = yb(32x192) @ thT^T(192x64) ----
  f32x4v o[2] = {{0.f, 0.f, 0.f, 0.f}, {0.f, 0.f, 0.f, 0.f}};
#pragma unroll
  for (int ks = 0; ks < 6; ++ks) {
    const bf16x8 af = *reinterpret_cast<const bf16x8*>(
        yb + (wr * 16 + l15) * 200 + ks * 32 + quad * 8);
#pragma unroll
    for (int t = 0; t < 2; ++t) {
      const bf16x8 bf = *reinterpret_cast<const bf16x8*>(
          thT + ((2 * wc + t) * 16 + l15) * 200 + ks * 32 + quad * 8);
      o[t] = __builtin_amdgcn_mfma_f32_16x16x32_bf16(af, bf, o[t], 0, 0, 0);
    }
  }
  // epilogue: relu + store (C-layout)
  float* gn = gcn + (size_t)n * VV * CC;
#pragma unroll
  for (int t = 0; t < 2; ++t) {
    const int col = (2 * wc + t) * 16 + l15;
#pragma unroll
    for (int r = 0; r < 4; ++r) {
      const int row = it * 32 + wr * 16 + quad * 4 + r;
      gn[(size_t)row * CC + col] = fmaxf(o[t][r], 0.f);
    }
  }
}

extern "C" void kernel_launch(void* const* d_in, const int* in_sizes, int n_in,
                              void* d_out, int out_size, void* d_ws, size_t ws_size,
                              hipStream_t stream) {
  const float* x = (const float*)d_in[0];      // (64,256,64)
  const float* a = (const float*)d_in[1];      // (64,)
  const float* theta = (const float*)d_in[2];  // (3,64,64)

  float* gcn = (float*)d_out;                                    // 1048576
  float* s = (float*)d_out + (size_t)NN * VV * CC;               // 4194304
  float* loss = (float*)d_out + (size_t)NN * VV * CC + (size_t)NN * VV * VV;

  const size_t xh_bytes = (size_t)NN * VV * FF * 2;  // 2 MB
  const size_t need = xh_bytes + 128;
  const bool pre = ws_size >= need;
  __half* xh = (__half*)d_ws;
  __half2* ah = (__half2*)((char*)d_ws + xh_bytes);

  hipMemsetAsync(loss, 0, sizeof(float), stream);
  if (pre) {
    cvt_kernel<<<512, 256, 0, stream>>>(x, a, (__half2*)xh, ah);
    gl_kernel<true><<<dim3(4, NN), 1024, 0, stream>>>(x, a, xh, ah, s, loss);
  } else {
    gl_kernel<false><<<dim3(4, NN), 1024, 0, stream>>>(x, a, xh, ah, s, loss);
  }
  gcn_kernel<<<dim3(8, NN), 256, 0, stream>>>(x, theta, s, gcn);
}